// Round 3
// baseline (137.212 us; speedup 1.0000x reference)
//
#include <hip/hip_runtime.h>

// Chamfer distance, B=8, N=M=4096, D=3, fp32 — 2-kernel fused pipeline.
//
// K1 pack:  both clouds -> float4 (x,y,z,|p|^2); init mins=+inf(uint), tickets=0, out=0.
// K2 main:  1024 blocks = 128 query-groups (512 queries) x 8 target-chunks (512 targets).
//           Each thread owns 2 queries; targets arrive via wave-uniform s_load
//           (scalar pipe, free of VALU cost). e = t2 - 2 q.t = 3 fma (+1 shared
//           v_mov for t2, amortized over the 2 queries). Block-local min, then
//           device-scope atomicMin into mins[]; per-group ticket; the last
//           chunk-block of each group finalizes: + |q|^2, clamp, scaled sum,
//           one atomicAdd into out.
//
// min(max(q2+t2-2qt,0)) == max(q2 + min(t2-2qt), 0): +q2 and max(.,0) are
// monotone, so they commute past the min.

#define CH_NPTS   4096
#define CH_HALF   32768            // 8*4096 points per cloud
#define CH_NQ     65536            // queries over both directions
#define CH_C      8                // target chunks per group
#define CH_TGT    (CH_NPTS / CH_C) // 512 targets per chunk
#define CH_GROUPS 128              // 65536 / 512 queries
#define CH_QPB    512              // queries per group

__device__ __forceinline__ unsigned fl2u(float f) {
    unsigned b = __float_as_uint(f);
    return (b & 0x80000000u) ? ~b : (b | 0x80000000u);
}
__device__ __forceinline__ float u2fl(unsigned u) {
    unsigned b = (u & 0x80000000u) ? (u ^ 0x80000000u) : ~u;
    return __uint_as_float(b);
}

// ws layout: [0,1MB) float4 packed[65536]; [1MB,+256KB) unsigned mins[65536];
//            then unsigned ticket[128].

__global__ __launch_bounds__(256) void chamfer_pack(
    const float* __restrict__ pred, const float* __restrict__ gt,
    float4* __restrict__ packed, unsigned* __restrict__ mins,
    unsigned* __restrict__ ticket, float* __restrict__ out)
{
    const int i = blockIdx.x * 256 + threadIdx.x;      // 0..65535
    if (i == 0) out[0] = 0.0f;
    if (i < CH_GROUPS) ticket[i] = 0u;
    mins[i] = 0xFFFFFFFFu;
    const int p = i & (CH_HALF - 1);
    const float* src = (i >> 15) ? gt : pred;
    const float x = src[p * 3 + 0];
    const float y = src[p * 3 + 1];
    const float z = src[p * 3 + 2];
    packed[i] = make_float4(x, y, z, fmaf(x, x, fmaf(y, y, z * z)));
}

__global__ __launch_bounds__(256) void chamfer_main(
    const float4* __restrict__ packed, unsigned* __restrict__ mins,
    unsigned* __restrict__ ticket, float* __restrict__ out)
{
    const int tid   = threadIdx.x;
    const int group = blockIdx.x >> 3;    // 0..127
    const int chunk = blockIdx.x & 7;     // 0..7
    const int dir   = group >> 6;         // 0..1
    const int b     = (group >> 3) & 7;   // 0..7

    // This thread's two queries (qid == packed index).
    const int qa = group * CH_QPB + tid;
    const int qb = qa + 256;
    const float4 Qa = packed[qa];
    const float4 Qb = packed[qb];
    const float ax = -2.f * Qa.x, ay = -2.f * Qa.y, az = -2.f * Qa.z;
    const float bx = -2.f * Qb.x, by = -2.f * Qb.y, bz = -2.f * Qb.z;

    const float4* __restrict__ t =
        packed + (dir ^ 1) * CH_HALF + b * CH_NPTS + chunk * CH_TGT;

    const float INF = 3.4028235e38f;
    float mA0 = INF, mA1 = INF, mB0 = INF, mB1 = INF;

    #pragma unroll 2
    for (int j = 0; j < CH_TGT; j += 8) {
        float ea[8], eb[8];
        #pragma unroll
        for (int k = 0; k < 8; ++k) {
            const float4 T = t[j + k];    // wave-uniform -> s_load (scalar pipe)
            const float tw = T.w;         // single v_mov, shared by both queries
            ea[k] = fmaf(ax, T.x, fmaf(ay, T.y, fmaf(az, T.z, tw)));
            eb[k] = fmaf(bx, T.x, fmaf(by, T.y, fmaf(bz, T.z, tw)));
        }
        mA0 = fminf(fminf(mA0, ea[0]), ea[1]);   // -> v_min3_f32
        mA1 = fminf(fminf(mA1, ea[2]), ea[3]);
        mA0 = fminf(fminf(mA0, ea[4]), ea[5]);
        mA1 = fminf(fminf(mA1, ea[6]), ea[7]);
        mB0 = fminf(fminf(mB0, eb[0]), eb[1]);
        mB1 = fminf(fminf(mB1, eb[2]), eb[3]);
        mB0 = fminf(fminf(mB0, eb[4]), eb[5]);
        mB1 = fminf(fminf(mB1, eb[6]), eb[7]);
    }

    atomicMin(&mins[qa], fl2u(fminf(mA0, mA1)));
    atomicMin(&mins[qb], fl2u(fminf(mB0, mB1)));

    __shared__ int  isLast;
    __shared__ float wsum[4];
    __syncthreads();                      // drains vmcnt: block's atomics complete
    if (tid == 0) {
        __threadfence();
        unsigned old = atomicAdd(&ticket[group], 1u);
        isLast = (old == CH_C - 1);
    }
    __syncthreads();
    if (!isLast) return;

    // Last chunk-block of this group: mins[] final for these 512 queries.
    __threadfence();
    const float ma = u2fl(atomicMin(&mins[qa], 0xFFFFFFFFu));  // coherent read
    const float mb = u2fl(atomicMin(&mins[qb], 0xFFFFFFFFu));
    const float da = fmaxf(Qa.w + ma, 0.0f);
    const float db = fmaxf(Qb.w + mb, 0.0f);

    float s = (da + db) * (1.0f / (8.0f * 4096.0f));
    #pragma unroll
    for (int off = 32; off > 0; off >>= 1)
        s += __shfl_down(s, off);
    if ((tid & 63) == 0) wsum[tid >> 6] = s;
    __syncthreads();
    if (tid == 0)
        atomicAdd(out, wsum[0] + wsum[1] + wsum[2] + wsum[3]);
}

extern "C" void kernel_launch(void* const* d_in, const int* in_sizes, int n_in,
                              void* d_out, int out_size, void* d_ws, size_t ws_size,
                              hipStream_t stream) {
    const float* pred = (const float*)d_in[0];
    const float* gt   = (const float*)d_in[1];
    float* out        = (float*)d_out;

    float4*   packed = (float4*)d_ws;
    unsigned* mins   = (unsigned*)((char*)d_ws + (size_t)CH_NQ * 16);
    unsigned* ticket = (unsigned*)((char*)d_ws + (size_t)CH_NQ * 16 + (size_t)CH_NQ * 4);

    chamfer_pack<<<CH_NQ / 256, 256, 0, stream>>>(pred, gt, packed, mins, ticket, out);
    chamfer_main<<<CH_GROUPS * CH_C, 256, 0, stream>>>(packed, mins, ticket, out);
}

// Round 13
// 87.914 us; speedup vs baseline: 1.5608x; 1.5608x over previous
//
#include <hip/hip_runtime.h>

// Chamfer distance, B=8, N=M=4096, D=3, fp32 — 3-kernel pipeline (R2 skeleton).
//
// K1 pack:   clouds -> SoA component arrays X,Y,Z,W(=|t|^2) [65536]; out=0.
// K2 main:   1024 blocks = 128 query-groups(512 q) x 8 target-chunks(512 t).
//            2 queries/thread. Targets stream via wave-uniform s_load_dwordx4
//            into SGPR quads. Inner math is written as f32x2 vector mul+add
//            chains — clang contracts these to v_pk_fma_f32 (packed 2xf32,
//            full-rate on CDNA): per 2 targets ~ 6 pk_fma + 2 min3 + W copy
//            ≈ 2.75 VALU/pair (worst case, scalarized: ~3.75/pair — still
//            2x better than R2's measured 7.5). NO inline asm: R8 burned a
//            run on a VOP3P op_sel default; instruction selection is now
//            entirely compiler-owned.
// K3 reduce: min over 8 chunks, + |q|^2, clamp, scaled sum -> atomicAdd.
//
// min(max(q2+t2-2qt,0)) == max(q2 + min(t2-2qt), 0)  (monotone ops commute
// past min), with -2 folded into the per-thread query broadcast registers.

#define CH_NPTS   4096
#define CH_HALF   32768            // points per cloud (8*4096)
#define CH_NQ     65536            // query ids over both directions
#define CH_C      8                // target chunks
#define CH_TGT    512              // targets per chunk
#define CH_GROUPS 128              // query groups of 512

typedef float f32x2 __attribute__((ext_vector_type(2)));
typedef float f32x4 __attribute__((ext_vector_type(4)));

// ws layout (floats): X[65536] | Y[65536] | Z[65536] | W[65536] | partial[8][65536]
// = 1MB packed + 2MB partial = 3MB.

__global__ __launch_bounds__(256) void chamfer_pack(
    const float* __restrict__ pred, const float* __restrict__ gt,
    float* __restrict__ X, float* __restrict__ Y,
    float* __restrict__ Z, float* __restrict__ W,
    float* __restrict__ out)
{
    const int i = blockIdx.x * 256 + threadIdx.x;      // 0..65535
    if (i == 0) out[0] = 0.0f;
    const int p = i & (CH_HALF - 1);
    const float* src = (i >> 15) ? gt : pred;
    const float x = src[p * 3 + 0];
    const float y = src[p * 3 + 1];
    const float z = src[p * 3 + 2];
    X[i] = x; Y[i] = y; Z[i] = z;
    W[i] = fmaf(x, x, fmaf(y, y, z * z));
}

__global__ __launch_bounds__(256) void chamfer_main(
    const float* __restrict__ X, const float* __restrict__ Y,
    const float* __restrict__ Z, const float* __restrict__ W,
    float* __restrict__ partial)
{
    const int tid   = threadIdx.x;
    const int group = blockIdx.x >> 3;    // 0..127
    const int chunk = blockIdx.x & 7;     // 0..7
    const int dir   = group >> 6;         // 0..1
    const int b     = (group >> 3) & 7;   // 0..7

    // Two queries per thread (qid == packed SoA index). Fold -2 into broadcast.
    const int qa = group * 512 + tid;
    const int qb = qa + 256;
    f32x2 axx, ayy, azz, bxx, byy, bzz;
    axx[0] = axx[1] = -2.f * X[qa];
    ayy[0] = ayy[1] = -2.f * Y[qa];
    azz[0] = azz[1] = -2.f * Z[qa];
    bxx[0] = bxx[1] = -2.f * X[qb];
    byy[0] = byy[1] = -2.f * Y[qb];
    bzz[0] = bzz[1] = -2.f * Z[qb];

    // Target chunk: opposite cloud, same batch. Wave-uniform addresses.
    const int toff = (dir ^ 1) * CH_HALF + b * CH_NPTS + chunk * CH_TGT;
    const f32x4* __restrict__ X4 = (const f32x4*)(X + toff);
    const f32x4* __restrict__ Y4 = (const f32x4*)(Y + toff);
    const f32x4* __restrict__ Z4 = (const f32x4*)(Z + toff);
    const f32x4* __restrict__ W4 = (const f32x4*)(W + toff);

    const float INF = 3.4028235e38f;
    float mA0 = INF, mA1 = INF, mB0 = INF, mB1 = INF;

    #pragma unroll 2
    for (int j = 0; j < CH_TGT / 4; ++j) {   // 4 targets per iteration
        const f32x4 Xs = X4[j];   // wave-uniform -> s_load_dwordx4 (SGPR quad)
        const f32x4 Ys = Y4[j];
        const f32x4 Zs = Z4[j];
        const f32x4 Ws = W4[j];

        #pragma unroll
        for (int h = 0; h < 2; ++h) {        // two f32x2 halves = 2 targets
            f32x2 xs, ys, zs, wv;
            xs[0] = Xs[2 * h]; xs[1] = Xs[2 * h + 1];
            ys[0] = Ys[2 * h]; ys[1] = Ys[2 * h + 1];
            zs[0] = Zs[2 * h]; zs[1] = Zs[2 * h + 1];
            wv[0] = Ws[2 * h]; wv[1] = Ws[2 * h + 1];

            // e = t2 - 2 q.t as packed mul+add chains; -ffp-contract=fast
            // turns each step into v_pk_fma_f32. One wv copy shared by both
            // queries.
            const f32x2 ea = xs * axx + (ys * ayy + (zs * azz + wv));
            const f32x2 eb = xs * bxx + (ys * byy + (zs * bzz + wv));

            // fminf chains -> v_min3_f32; two independent accumulators per
            // query keep the dependency chains short.
            if (h) {
                mA1 = fminf(fminf(mA1, ea[0]), ea[1]);
                mB1 = fminf(fminf(mB1, eb[0]), eb[1]);
            } else {
                mA0 = fminf(fminf(mA0, ea[0]), ea[1]);
                mB0 = fminf(fminf(mB0, eb[0]), eb[1]);
            }
        }
    }

    partial[chunk * CH_NQ + qa] = fminf(mA0, mA1);
    partial[chunk * CH_NQ + qb] = fminf(mB0, mB1);
}

__global__ __launch_bounds__(256) void chamfer_reduce(
    const float* __restrict__ W, const float* __restrict__ partial,
    float* __restrict__ out)
{
    __shared__ float wsum[4];
    const int i = blockIdx.x * 256 + threadIdx.x;      // query id 0..65535

    float m = partial[i];
    #pragma unroll
    for (int c = 1; c < CH_C; ++c)
        m = fminf(m, partial[c * CH_NQ + i]);
    const float d = fmaxf(W[i] + m, 0.0f);

    float s = d * (1.0f / (8.0f * 4096.0f));
    #pragma unroll
    for (int off = 32; off > 0; off >>= 1)
        s += __shfl_down(s, off);

    if ((threadIdx.x & 63) == 0) wsum[threadIdx.x >> 6] = s;
    __syncthreads();
    if (threadIdx.x == 0)
        atomicAdd(out, wsum[0] + wsum[1] + wsum[2] + wsum[3]);
}

extern "C" void kernel_launch(void* const* d_in, const int* in_sizes, int n_in,
                              void* d_out, int out_size, void* d_ws, size_t ws_size,
                              hipStream_t stream) {
    const float* pred = (const float*)d_in[0];
    const float* gt   = (const float*)d_in[1];
    float* out        = (float*)d_out;

    float* X       = (float*)d_ws;
    float* Y       = X + CH_NQ;
    float* Z       = Y + CH_NQ;
    float* W       = Z + CH_NQ;
    float* partial = W + CH_NQ;    // 8 * 65536 floats

    chamfer_pack  <<<CH_NQ / 256, 256, 0, stream>>>(pred, gt, X, Y, Z, W, out);
    chamfer_main  <<<CH_GROUPS * CH_C, 256, 0, stream>>>(X, Y, Z, W, partial);
    chamfer_reduce<<<CH_NQ / 256, 256, 0, stream>>>(W, partial, out);
}

// Round 15
// 85.787 us; speedup vs baseline: 1.5994x; 1.0248x over previous
//
#include <hip/hip_runtime.h>

// Chamfer distance, B=8, N=M=4096, D=3, fp32 — 3-kernel pipeline (R2 skeleton).
//
// K1 pack:   clouds -> SoA component arrays X,Y,Z,W(=|t|^2) [65536]; out=0.
// K2 main:   1024 blocks = 128 query-groups(512 q) x 8 target-chunks(512 t).
//            2 queries/thread. Targets stream via wave-uniform s_load_dwordx4
//            into SGPR quads. Inner math: __builtin_elementwise_fma on f32x2
//            (llvm.fma.v2f32 -> v_pk_fma_f32 on gfx950's packed-f32 ALU;
//            worst case two v_fma_f32 — no regression vs R13). Per 2 targets:
//            6 pk_fma + 2 min3 + 1 W copy ≈ 2.25 VALU/pair.
//            Plain store of per-(chunk,query) min. No atomics in main.
// K3 reduce: min over 8 chunks, + |q|^2, clamp, scaled sum -> atomicAdd.
//
// min(max(q2+t2-2qt,0)) == max(q2 + min(t2-2qt), 0)  (monotone ops commute
// past min), with -2 folded into the per-thread query broadcast registers.
//
// R13 post-mortem: passed at total 87.9 µs; decomposition vs R2/R3 puts main
// at ~30-35 µs, 2x above the packed-math model — consistent with clang
// scalarizing the f32x2 mul+add chains. This round forces FMA formation via
// __builtin_elementwise_fma; zero other changes (attribution experiment).

#define CH_NPTS   4096
#define CH_HALF   32768            // points per cloud (8*4096)
#define CH_NQ     65536            // query ids over both directions
#define CH_C      8                // target chunks
#define CH_TGT    512              // targets per chunk
#define CH_GROUPS 128              // query groups of 512

typedef float f32x2 __attribute__((ext_vector_type(2)));
typedef float f32x4 __attribute__((ext_vector_type(4)));

// ws layout (floats): X[65536] | Y[65536] | Z[65536] | W[65536] | partial[8][65536]
// = 1MB packed + 2MB partial = 3MB.

__global__ __launch_bounds__(256) void chamfer_pack(
    const float* __restrict__ pred, const float* __restrict__ gt,
    float* __restrict__ X, float* __restrict__ Y,
    float* __restrict__ Z, float* __restrict__ W,
    float* __restrict__ out)
{
    const int i = blockIdx.x * 256 + threadIdx.x;      // 0..65535
    if (i == 0) out[0] = 0.0f;
    const int p = i & (CH_HALF - 1);
    const float* src = (i >> 15) ? gt : pred;
    const float x = src[p * 3 + 0];
    const float y = src[p * 3 + 1];
    const float z = src[p * 3 + 2];
    X[i] = x; Y[i] = y; Z[i] = z;
    W[i] = fmaf(x, x, fmaf(y, y, z * z));
}

__global__ __launch_bounds__(256) void chamfer_main(
    const float* __restrict__ X, const float* __restrict__ Y,
    const float* __restrict__ Z, const float* __restrict__ W,
    float* __restrict__ partial)
{
    const int tid   = threadIdx.x;
    const int group = blockIdx.x >> 3;    // 0..127
    const int chunk = blockIdx.x & 7;     // 0..7
    const int dir   = group >> 6;         // 0..1
    const int b     = (group >> 3) & 7;   // 0..7

    // Two queries per thread (qid == packed SoA index). Fold -2 into broadcast.
    const int qa = group * 512 + tid;
    const int qb = qa + 256;
    f32x2 axx, ayy, azz, bxx, byy, bzz;
    axx[0] = axx[1] = -2.f * X[qa];
    ayy[0] = ayy[1] = -2.f * Y[qa];
    azz[0] = azz[1] = -2.f * Z[qa];
    bxx[0] = bxx[1] = -2.f * X[qb];
    byy[0] = byy[1] = -2.f * Y[qb];
    bzz[0] = bzz[1] = -2.f * Z[qb];

    // Target chunk: opposite cloud, same batch. Wave-uniform addresses.
    const int toff = (dir ^ 1) * CH_HALF + b * CH_NPTS + chunk * CH_TGT;
    const f32x4* __restrict__ X4 = (const f32x4*)(X + toff);
    const f32x4* __restrict__ Y4 = (const f32x4*)(Y + toff);
    const f32x4* __restrict__ Z4 = (const f32x4*)(Z + toff);
    const f32x4* __restrict__ W4 = (const f32x4*)(W + toff);

    const float INF = 3.4028235e38f;
    float mA0 = INF, mA1 = INF, mB0 = INF, mB1 = INF;

    #pragma unroll 2
    for (int j = 0; j < CH_TGT / 4; ++j) {   // 4 targets per iteration
        const f32x4 Xs = X4[j];   // wave-uniform -> s_load_dwordx4 (SGPR quad)
        const f32x4 Ys = Y4[j];
        const f32x4 Zs = Z4[j];
        const f32x4 Ws = W4[j];

        #pragma unroll
        for (int h = 0; h < 2; ++h) {        // two f32x2 halves = 2 targets
            f32x2 xs, ys, zs, wv;
            xs[0] = Xs[2 * h]; xs[1] = Xs[2 * h + 1];
            ys[0] = Ys[2 * h]; ys[1] = Ys[2 * h + 1];
            zs[0] = Zs[2 * h]; zs[1] = Zs[2 * h + 1];
            wv[0] = Ws[2 * h]; wv[1] = Ws[2 * h + 1];

            // e = t2 - 2 q.t: explicit packed FMA chain (llvm.fma.v2f32 ->
            // v_pk_fma_f32). One wv copy shared by both queries.
            const f32x2 ea = __builtin_elementwise_fma(
                xs, axx, __builtin_elementwise_fma(
                    ys, ayy, __builtin_elementwise_fma(zs, azz, wv)));
            const f32x2 eb = __builtin_elementwise_fma(
                xs, bxx, __builtin_elementwise_fma(
                    ys, byy, __builtin_elementwise_fma(zs, bzz, wv)));

            // fminf chains -> v_min3_f32; two independent accumulators per
            // query keep the dependency chains short.
            if (h) {
                mA1 = fminf(fminf(mA1, ea[0]), ea[1]);
                mB1 = fminf(fminf(mB1, eb[0]), eb[1]);
            } else {
                mA0 = fminf(fminf(mA0, ea[0]), ea[1]);
                mB0 = fminf(fminf(mB0, eb[0]), eb[1]);
            }
        }
    }

    partial[chunk * CH_NQ + qa] = fminf(mA0, mA1);
    partial[chunk * CH_NQ + qb] = fminf(mB0, mB1);
}

__global__ __launch_bounds__(256) void chamfer_reduce(
    const float* __restrict__ W, const float* __restrict__ partial,
    float* __restrict__ out)
{
    __shared__ float wsum[4];
    const int i = blockIdx.x * 256 + threadIdx.x;      // query id 0..65535

    float m = partial[i];
    #pragma unroll
    for (int c = 1; c < CH_C; ++c)
        m = fminf(m, partial[c * CH_NQ + i]);
    const float d = fmaxf(W[i] + m, 0.0f);

    float s = d * (1.0f / (8.0f * 4096.0f));
    #pragma unroll
    for (int off = 32; off > 0; off >>= 1)
        s += __shfl_down(s, off);

    if ((threadIdx.x & 63) == 0) wsum[threadIdx.x >> 6] = s;
    __syncthreads();
    if (threadIdx.x == 0)
        atomicAdd(out, wsum[0] + wsum[1] + wsum[2] + wsum[3]);
}

extern "C" void kernel_launch(void* const* d_in, const int* in_sizes, int n_in,
                              void* d_out, int out_size, void* d_ws, size_t ws_size,
                              hipStream_t stream) {
    const float* pred = (const float*)d_in[0];
    const float* gt   = (const float*)d_in[1];
    float* out        = (float*)d_out;

    float* X       = (float*)d_ws;
    float* Y       = X + CH_NQ;
    float* Z       = Y + CH_NQ;
    float* W       = Z + CH_NQ;
    float* partial = W + CH_NQ;    // 8 * 65536 floats

    chamfer_pack  <<<CH_NQ / 256, 256, 0, stream>>>(pred, gt, X, Y, Z, W, out);
    chamfer_main  <<<CH_GROUPS * CH_C, 256, 0, stream>>>(X, Y, Z, W, partial);
    chamfer_reduce<<<CH_NQ / 256, 256, 0, stream>>>(W, partial, out);
}

// Round 16
// 84.142 us; speedup vs baseline: 1.6307x; 1.0196x over previous
//
#include <hip/hip_runtime.h>

// Chamfer distance, B=8, N=M=4096, D=3, fp32 — 3-kernel pipeline.
//
// R15 post-mortem: main stuck at ~33 µs across 2x-different VALU models →
// scalar-load latency-bound (4 s_load_dwordx4 @ ~100-400cy vs 40cy VALU per
// iter, only 4 waves/SIMD of cover). This round: targets staged in LDS
// (wave-uniform ds_read_b128 broadcast, LDS pipe overlaps VALU, operands in
// VGPRs -> zero SGPR copies) + CH_C=16 (2048 blocks = 8 waves/SIMD cover).
//
// K1 pack:   clouds -> SoA X,Y,Z,W(=|t|^2) [65536 each, contiguous]; out=0.
// K2 main:   2048 blocks = 128 query-groups(512 q) x 16 target-chunks(256 t).
//            Block stages its 4KB chunk to LDS; 2 queries/thread; inner math
//            f32x2 __builtin_elementwise_fma chains (v_pk_fma_f32):
//            per 4 targets: 12 pk_fma + 4 min3 = 2.0 VALU/pair.
// K3 reduce: min over 16 chunks, + |q|^2, clamp, scaled sum -> atomicAdd.
//
// min(max(q2+t2-2qt,0)) == max(q2 + min(t2-2qt), 0)  (monotone ops commute
// past min), with -2 folded into the per-thread query broadcast registers.

#define CH_NPTS   4096
#define CH_HALF   32768            // points per cloud (8*4096)
#define CH_NQ     65536            // query ids over both directions
#define CH_C      16               // target chunks
#define CH_TGT    256              // targets per chunk
#define CH_GROUPS 128              // query groups of 512

typedef float f32x2 __attribute__((ext_vector_type(2)));
typedef float f32x4 __attribute__((ext_vector_type(4)));

// ws layout (floats): X[65536] | Y[65536] | Z[65536] | W[65536] |
//                     partial[16][65536]  = 1MB + 4MB.

__global__ __launch_bounds__(256) void chamfer_pack(
    const float* __restrict__ pred, const float* __restrict__ gt,
    float* __restrict__ X, float* __restrict__ Y,
    float* __restrict__ Z, float* __restrict__ W,
    float* __restrict__ out)
{
    const int i = blockIdx.x * 256 + threadIdx.x;      // 0..65535
    if (i == 0) out[0] = 0.0f;
    const int p = i & (CH_HALF - 1);
    const float* src = (i >> 15) ? gt : pred;
    const float x = src[p * 3 + 0];
    const float y = src[p * 3 + 1];
    const float z = src[p * 3 + 2];
    X[i] = x; Y[i] = y; Z[i] = z;
    W[i] = fmaf(x, x, fmaf(y, y, z * z));
}

// X = ws base; Y/Z/W are X + k*CH_NQ (contiguous SoA) — main uses that to
// avoid dynamically-indexed pointer arrays (scratch risk).
__global__ __launch_bounds__(256, 8) void chamfer_main(
    const float* __restrict__ X, float* __restrict__ partial)
{
    __shared__ alignas(16) float sT[4][CH_TGT];   // X,Y,Z,W chunk: 4 KB

    const int tid   = threadIdx.x;
    const int group = blockIdx.x >> 4;    // 0..127
    const int chunk = blockIdx.x & 15;    // 0..15
    const int dir   = group >> 6;         // 0..1
    const int b     = (group >> 3) & 7;   // 0..7

    // Stage target chunk (opposite cloud, same batch) to LDS:
    // 256 threads x one float4 (coalesced 16B/lane).
    const int toff = (dir ^ 1) * CH_HALF + b * CH_NPTS + chunk * CH_TGT;
    {
        const int arr = tid >> 6;         // 0..3 -> X,Y,Z,W
        const int idx = tid & 63;         // float4 index within 256 floats
        reinterpret_cast<float4*>(sT)[tid] =
            reinterpret_cast<const float4*>(X + arr * CH_NQ + toff)[idx];
    }

    // Two queries per thread (qid == SoA index). Fold -2 into broadcasts.
    const int qa = group * 512 + tid;
    const int qb = qa + 256;
    f32x2 axx, ayy, azz, bxx, byy, bzz;
    axx[0] = axx[1] = -2.f * X[qa];
    ayy[0] = ayy[1] = -2.f * X[CH_NQ + qa];
    azz[0] = azz[1] = -2.f * X[2 * CH_NQ + qa];
    bxx[0] = bxx[1] = -2.f * X[qb];
    byy[0] = byy[1] = -2.f * X[CH_NQ + qb];
    bzz[0] = bzz[1] = -2.f * X[2 * CH_NQ + qb];

    __syncthreads();

    const f32x4* __restrict__ Xl = reinterpret_cast<const f32x4*>(&sT[0][0]);
    const f32x4* __restrict__ Yl = reinterpret_cast<const f32x4*>(&sT[1][0]);
    const f32x4* __restrict__ Zl = reinterpret_cast<const f32x4*>(&sT[2][0]);
    const f32x4* __restrict__ Wl = reinterpret_cast<const f32x4*>(&sT[3][0]);

    const float INF = 3.4028235e38f;
    float mA0 = INF, mA1 = INF, mB0 = INF, mB1 = INF;

    #pragma unroll 2
    for (int j = 0; j < CH_TGT / 4; ++j) {   // 4 targets per iteration
        const f32x4 Xs = Xl[j];   // wave-uniform ds_read_b128 (broadcast)
        const f32x4 Ys = Yl[j];
        const f32x4 Zs = Zl[j];
        const f32x4 Ws = Wl[j];

        #pragma unroll
        for (int h = 0; h < 2; ++h) {        // two f32x2 halves = 2 targets
            f32x2 xs, ys, zs, wv;
            xs[0] = Xs[2 * h]; xs[1] = Xs[2 * h + 1];
            ys[0] = Ys[2 * h]; ys[1] = Ys[2 * h + 1];
            zs[0] = Zs[2 * h]; zs[1] = Zs[2 * h + 1];
            wv[0] = Ws[2 * h]; wv[1] = Ws[2 * h + 1];

            // e = t2 - 2 q.t : packed FMA chains (v_pk_fma_f32); operands
            // already in VGPRs from LDS -> no SGPR->VGPR copies at all.
            const f32x2 ea = __builtin_elementwise_fma(
                xs, axx, __builtin_elementwise_fma(
                    ys, ayy, __builtin_elementwise_fma(zs, azz, wv)));
            const f32x2 eb = __builtin_elementwise_fma(
                xs, bxx, __builtin_elementwise_fma(
                    ys, byy, __builtin_elementwise_fma(zs, bzz, wv)));

            if (h) {
                mA1 = fminf(fminf(mA1, ea[0]), ea[1]);   // -> v_min3_f32
                mB1 = fminf(fminf(mB1, eb[0]), eb[1]);
            } else {
                mA0 = fminf(fminf(mA0, ea[0]), ea[1]);
                mB0 = fminf(fminf(mB0, eb[0]), eb[1]);
            }
        }
    }

    partial[chunk * CH_NQ + qa] = fminf(mA0, mA1);
    partial[chunk * CH_NQ + qb] = fminf(mB0, mB1);
}

__global__ __launch_bounds__(256) void chamfer_reduce(
    const float* __restrict__ W, const float* __restrict__ partial,
    float* __restrict__ out)
{
    __shared__ float wsum[4];
    const int i = blockIdx.x * 256 + threadIdx.x;      // query id 0..65535

    float m = partial[i];
    #pragma unroll
    for (int c = 1; c < CH_C; ++c)
        m = fminf(m, partial[c * CH_NQ + i]);
    const float d = fmaxf(W[i] + m, 0.0f);

    float s = d * (1.0f / (8.0f * 4096.0f));
    #pragma unroll
    for (int off = 32; off > 0; off >>= 1)
        s += __shfl_down(s, off);

    if ((threadIdx.x & 63) == 0) wsum[threadIdx.x >> 6] = s;
    __syncthreads();
    if (threadIdx.x == 0)
        atomicAdd(out, wsum[0] + wsum[1] + wsum[2] + wsum[3]);
}

extern "C" void kernel_launch(void* const* d_in, const int* in_sizes, int n_in,
                              void* d_out, int out_size, void* d_ws, size_t ws_size,
                              hipStream_t stream) {
    const float* pred = (const float*)d_in[0];
    const float* gt   = (const float*)d_in[1];
    float* out        = (float*)d_out;

    float* X       = (float*)d_ws;
    float* Y       = X + CH_NQ;
    float* Z       = Y + CH_NQ;
    float* W       = Z + CH_NQ;
    float* partial = W + CH_NQ;    // 16 * 65536 floats

    chamfer_pack  <<<CH_NQ / 256, 256, 0, stream>>>(pred, gt, X, Y, Z, W, out);
    chamfer_main  <<<CH_GROUPS * CH_C, 256, 0, stream>>>(X, partial);
    chamfer_reduce<<<CH_NQ / 256, 256, 0, stream>>>(W, partial, out);
}